// Round 6
// baseline (135.390 us; speedup 1.0000x reference)
//
#include <hip/hip_runtime.h>

typedef short short8 __attribute__((ext_vector_type(8)));
typedef float f32x4 __attribute__((ext_vector_type(4)));

// K = 256 (ones-column folded into per-rule bias); p materialized bf16.

// workspace layout (bytes)
#define OFF_CP   0ULL        // cp bf16 [1024][256]    524288
#define OFF_P    524288ULL   // p  bf16 [16384][256]  8388608
#define OFF_CB   8912896ULL  // bias f32 [1024]          4096
#define OFF_A2   8916992ULL  // a2 f32  [1024][4]       16384
#define OFF_C2   8933376ULL  // c2 f32  [1024][4]       16384
#define OFF_IX   8949760ULL  // packed fidx u32 [1024]   4096
#define OFF_NUM  8953856ULL  // num f32 [16384]         65536
#define OFF_DEN  9019392ULL  // den f32 [16384]         65536

#define XS 65  // xa LDS stride: gather bank = (row + f) % 32 -> ~2-way (free)

__device__ __forceinline__ unsigned short f2bf(float f) {
  unsigned u = __float_as_uint(f);
  return (unsigned short)((u + 0x7FFFu + ((u >> 16) & 1u)) >> 16);
}

// ---- prep: p materialization, cp->bf16 + bias, rule consts, zero num/den ----
__global__ __launch_bounds__(256) void prep_kernel(
    const float* __restrict__ x, const float* __restrict__ att,
    const float* __restrict__ pp, const float* __restrict__ th,
    const float* __restrict__ sg, const float* __restrict__ mk,
    const float* __restrict__ cp, const int* __restrict__ fidx,
    const int* __restrict__ pairs, unsigned char* __restrict__ ws)
{
  __shared__ float xa[64 * XS];
  unsigned short* p_out  = (unsigned short*)(ws + OFF_P);
  unsigned short* cp_out = (unsigned short*)(ws + OFF_CP);
  float* cbo = (float*)(ws + OFF_CB);
  float* a2o = (float*)(ws + OFF_A2);
  float* c2o = (float*)(ws + OFF_C2);
  unsigned* ixo = (unsigned*)(ws + OFF_IX);
  int bid = blockIdx.x, t = threadIdx.x;

  if (bid < 256) {  // p-writer: 64 batch rows per block, vectorized
    int b0 = bid * 64;
#pragma unroll
    for (int i = 0; i < 4; ++i) {
      int idx = t + i * 256, row = idx >> 4, c4 = idx & 15;
      float4 a4 = ((const float4*)att)[c4];
      float4 v = ((const float4*)(x + (size_t)(b0 + row) * 64))[c4];
      float* dst = &xa[row * XS + c4 * 4];
      dst[0] = v.x * a4.x; dst[1] = v.y * a4.y;
      dst[2] = v.z * a4.z; dst[3] = v.w * a4.w;
    }
    __syncthreads();
    int row2 = t >> 2, q = t & 3;
    const float* xr2 = &xa[row2 * XS];
    unsigned short* po = p_out + (size_t)(b0 + row2) * 256;
#pragma unroll
    for (int ks = 0; ks < 8; ++ks) {
      int fb = ks * 32 + q * 8;
      short8 vp;
      if (ks < 2) {                 // raw x_att
#pragma unroll
        for (int j = 0; j < 8; ++j) vp[j] = f2bf(xr2[fb + j]);
      } else if (ks < 4) {          // squares
#pragma unroll
        for (int j = 0; j < 8; ++j) { float u = xr2[fb - 64 + j]; vp[j] = f2bf(u * u); }
      } else {                      // interaction pairs
        const int2* pr = (const int2*)pairs + (fb - 128);
#pragma unroll
        for (int j = 0; j < 8; ++j) {
          int2 pq = pr[j];
          vp[j] = f2bf(xr2[pq.x] * xr2[pq.y]);
        }
      }
      *(short8*)(po + fb) = vp;
    }
  } else if (bid < 512) {  // cp cols 0..255 -> bf16 [1024][256]
    int e = (bid - 256) * 1024 + t * 4;
    int r = e >> 8, c = e & 255;
    const float* src = cp + (size_t)r * 257 + c;
#pragma unroll
    for (int q = 0; q < 4; ++q) cp_out[e + q] = f2bf(src[q]);
  } else if (bid < 516) {  // rule consts + bias
    int r = (bid - 512) * 256 + t;
    float p = pp[r];
    unsigned pk = 0;
#pragma unroll
    for (int l = 0; l < 4; ++l) {
      float m = mk[r * 4 + l], s = sg[r * 4 + l], tt = th[r * 4 + l];
      float A, C;
      if (m != 0.f) { A = -1.44269504f * p * s; C = 1.44269504f * p * s * tt; }
      else          { A = 0.f;                  C = -126.f; }  // exp2(-126) ~ 0 -> factor 1
      a2o[r * 4 + l] = A; c2o[r * 4 + l] = C;
      pk |= ((unsigned)fidx[r * 4 + l] & 0xFFu) << (8 * l);
    }
    ixo[r] = pk;
    cbo[r] = cp[(size_t)r * 257 + 256];  // ones-column coefficient
  } else {  // zero num/den (ws is re-poisoned 0xAA before every call)
    float* dst = (float*)(ws + (bid == 516 ? OFF_NUM : OFF_DEN));
#pragma unroll
    for (int q = 0; q < 64; ++q) dst[q * 256 + t] = 0.f;
  }
}

// ---- main: C[rule][batch] = cp . p^T (K=256), operands streamed from global,
// fused firing. grid (256 b x 8 r); block = 128 rules x 64 batches; no K-loop
// barriers, no operand LDS. launch_bounds (256,4): acc=32 AGPR, ~dozens VGPR.
__global__ __launch_bounds__(256, 4) void main_kernel(
    const unsigned char* __restrict__ ws,
    const float* __restrict__ x, const float* __restrict__ att,
    float* __restrict__ numg, float* __restrict__ deng)
{
  __shared__ float xa[64 * XS];  // 16640 B — the only LDS

  const unsigned short* CP = (const unsigned short*)(ws + OFF_CP);
  const unsigned short* P  = (const unsigned short*)(ws + OFF_P);
  const float* CB = (const float*)(ws + OFF_CB);
  const float4* A2p = (const float4*)(ws + OFF_A2);
  const float4* C2p = (const float4*)(ws + OFF_C2);
  const unsigned* IX = (const unsigned*)(ws + OFF_IX);

  int t = threadIdx.x, l = t & 63, w = t >> 6;
  int g = l >> 4, lr = l & 15;
  int b0 = blockIdx.x * 64, r0 = blockIdx.y * 128;

  {  // stage x_att tile (64 rows x 64 f32) — needed by the firing epilogue
#pragma unroll
    for (int i = 0; i < 4; ++i) {
      int idx = t + i * 256, row = idx >> 4, c4 = idx & 15;
      float4 a4 = ((const float4*)att)[c4];
      float4 v = ((const float4*)(x + (size_t)(b0 + row) * 64))[c4];
      float* dst = &xa[row * XS + c4 * 4];
      dst[0] = v.x * a4.x; dst[1] = v.y * a4.y;
      dst[2] = v.z * a4.z; dst[3] = v.w * a4.w;
    }
  }
  __syncthreads();

  // k-invariant per-lane fragment bases; ks advances by 64 B -> immediate offsets
  const short8* aB0 = (const short8*)(CP + (size_t)(r0 + w * 32 + lr) * 256 + g * 8);
  const short8* aB1 = (const short8*)(CP + (size_t)(r0 + w * 32 + 16 + lr) * 256 + g * 8);
  const short8* bB0 = (const short8*)(P + (size_t)(b0 + lr) * 256 + g * 8);
  const short8* bB1 = (const short8*)(P + (size_t)(b0 + 16 + lr) * 256 + g * 8);
  const short8* bB2 = (const short8*)(P + (size_t)(b0 + 32 + lr) * 256 + g * 8);
  const short8* bB3 = (const short8*)(P + (size_t)(b0 + 48 + lr) * 256 + g * 8);

  f32x4 acc[2][4];
#pragma unroll
  for (int mi = 0; mi < 2; ++mi)
#pragma unroll
    for (int ni = 0; ni < 4; ++ni)
      acc[mi][ni] = (f32x4){0.f, 0.f, 0.f, 0.f};

#pragma unroll
  for (int ks = 0; ks < 8; ++ks) {
    int ko = ks * 4;  // short8 units: 32 elems = 4 short8
    short8 a0 = aB0[ko], a1 = aB1[ko];
    short8 f0 = bB0[ko], f1 = bB1[ko], f2 = bB2[ko], f3 = bB3[ko];
    acc[0][0] = __builtin_amdgcn_mfma_f32_16x16x32_bf16(a0, f0, acc[0][0], 0, 0, 0);
    acc[0][1] = __builtin_amdgcn_mfma_f32_16x16x32_bf16(a0, f1, acc[0][1], 0, 0, 0);
    acc[0][2] = __builtin_amdgcn_mfma_f32_16x16x32_bf16(a0, f2, acc[0][2], 0, 0, 0);
    acc[0][3] = __builtin_amdgcn_mfma_f32_16x16x32_bf16(a0, f3, acc[0][3], 0, 0, 0);
    acc[1][0] = __builtin_amdgcn_mfma_f32_16x16x32_bf16(a1, f0, acc[1][0], 0, 0, 0);
    acc[1][1] = __builtin_amdgcn_mfma_f32_16x16x32_bf16(a1, f1, acc[1][1], 0, 0, 0);
    acc[1][2] = __builtin_amdgcn_mfma_f32_16x16x32_bf16(a1, f2, acc[1][2], 0, 0, 0);
    acc[1][3] = __builtin_amdgcn_mfma_f32_16x16x32_bf16(a1, f3, acc[1][3], 0, 0, 0);
  }

  // ---- fused firing epilogue. C layout: row = rule = w*32+mi*16+g*4+j (g-uniform
  // per 16 lanes), col = batch = ni*16+lr. Gather bank = (16ni+lr+f)%32: ~2-way.
  float num[4] = {0.f, 0.f, 0.f, 0.f}, den[4] = {0.f, 0.f, 0.f, 0.f};
#pragma unroll
  for (int mi = 0; mi < 2; ++mi) {
#pragma unroll
    for (int j = 0; j < 4; ++j) {
      int rule = r0 + w * 32 + mi * 16 + (g << 2) + j;
      float4 A2 = A2p[rule], C2 = C2p[rule];
      unsigned pk = IX[rule];
      float bias = CB[rule];
      int f0 = pk & 255, f1 = (pk >> 8) & 255, f2 = (pk >> 16) & 255, f3 = pk >> 24;
#pragma unroll
      for (int ni = 0; ni < 4; ++ni) {
        const float* xr = &xa[(ni * 16 + lr) * XS];
        float D = 1.f;
        float e0 = exp2f(fmaf(A2.x, xr[f0], C2.x)); D = fmaf(D, e0, D);
        float e1 = exp2f(fmaf(A2.y, xr[f1], C2.y)); D = fmaf(D, e1, D);
        float e2 = exp2f(fmaf(A2.z, xr[f2], C2.z)); D = fmaf(D, e2, D);
        float e3 = exp2f(fmaf(A2.w, xr[f3], C2.w)); D = fmaf(D, e3, D);
        float fir = __builtin_amdgcn_rcpf(D);
        num[ni] = fmaf(fir, acc[mi][ni][j] + bias, num[ni]);
        den[ni] += fir;
      }
    }
  }

  // reduce over the 4 lane-groups (g) which hold different rules of same batch col
#pragma unroll
  for (int ni = 0; ni < 4; ++ni) {
    float n = num[ni], d = den[ni];
    n += __shfl_xor(n, 16, 64); n += __shfl_xor(n, 32, 64);
    d += __shfl_xor(d, 16, 64); d += __shfl_xor(d, 32, 64);
    num[ni] = n; den[ni] = d;
  }
  float nv = 0.f, dv = 0.f;
#pragma unroll
  for (int ni = 0; ni < 4; ++ni)
    if (g == ni) { nv = num[ni]; dv = den[ni]; }
  atomicAdd(&numg[b0 + (g << 4) + lr], nv);
  atomicAdd(&deng[b0 + (g << 4) + lr], dv);
}

// ---------------- finalize ----------------
__global__ __launch_bounds__(256) void fin_kernel(
    const float* __restrict__ numg, const float* __restrict__ deng,
    float* __restrict__ y)
{
  int i = blockIdx.x * 256 + threadIdx.x;
  y[i] = numg[i] / (deng[i] + 1e-8f);
}

extern "C" void kernel_launch(void* const* d_in, const int* in_sizes, int n_in,
                              void* d_out, int out_size, void* d_ws, size_t ws_size,
                              hipStream_t stream) {
  (void)in_sizes; (void)n_in; (void)out_size; (void)ws_size;
  const float* x    = (const float*)d_in[0];
  const float* att  = (const float*)d_in[1];
  const float* pp   = (const float*)d_in[2];
  const float* th   = (const float*)d_in[3];
  const float* sg   = (const float*)d_in[4];
  const float* mk   = (const float*)d_in[5];
  const float* cp   = (const float*)d_in[6];
  const int* fidx   = (const int*)d_in[7];
  const int* pairs  = (const int*)d_in[8];
  unsigned char* ws = (unsigned char*)d_ws;
  float* numg = (float*)(ws + OFF_NUM);
  float* deng = (float*)(ws + OFF_DEN);

  prep_kernel<<<518, 256, 0, stream>>>(x, att, pp, th, sg, mk, cp, fidx, pairs, ws);
  main_kernel<<<dim3(256, 8), 256, 0, stream>>>(ws, x, att, numg, deng);
  fin_kernel<<<64, 256, 0, stream>>>(numg, deng, (float*)d_out);
}

// Round 7
// 118.157 us; speedup vs baseline: 1.1458x; 1.1458x over previous
//
#include <hip/hip_runtime.h>

typedef short short8 __attribute__((ext_vector_type(8)));
typedef float f32x4 __attribute__((ext_vector_type(4)));

// K = 256 (ones-column folded into per-rule bias); p materialized bf16.

// workspace layout (bytes)
#define OFF_CP   0ULL        // cp bf16 [1024][256]    524288
#define OFF_P    524288ULL   // p  bf16 [16384][256]  8388608
#define OFF_CB   8912896ULL  // bias f32 [1024]          4096
#define OFF_A2   8916992ULL  // a2 f32  [1024][4]       16384
#define OFF_C2   8933376ULL  // c2 f32  [1024][4]       16384
#define OFF_IX   8949760ULL  // packed fidx u32 [1024]   4096
#define OFF_NUM  8953856ULL  // num f32 [16384]         65536
#define OFF_DEN  9019392ULL  // den f32 [16384]         65536

#define XS 65  // xa LDS stride: gather bank = (row + f) % 32 -> ~2-way (free)

#define MF(a, b, c) __builtin_amdgcn_mfma_f32_16x16x32_bf16(a, b, c, 0, 0, 0)

__device__ __forceinline__ unsigned short f2bf(float f) {
  unsigned u = __float_as_uint(f);
  return (unsigned short)((u + 0x7FFFu + ((u >> 16) & 1u)) >> 16);
}

// ---- prep: p materialization, cp->bf16 + bias, rule consts, zero num/den ----
__global__ __launch_bounds__(256) void prep_kernel(
    const float* __restrict__ x, const float* __restrict__ att,
    const float* __restrict__ pp, const float* __restrict__ th,
    const float* __restrict__ sg, const float* __restrict__ mk,
    const float* __restrict__ cp, const int* __restrict__ fidx,
    const int* __restrict__ pairs, unsigned char* __restrict__ ws)
{
  __shared__ float xa[64 * XS];
  unsigned short* p_out  = (unsigned short*)(ws + OFF_P);
  unsigned short* cp_out = (unsigned short*)(ws + OFF_CP);
  float* cbo = (float*)(ws + OFF_CB);
  float* a2o = (float*)(ws + OFF_A2);
  float* c2o = (float*)(ws + OFF_C2);
  unsigned* ixo = (unsigned*)(ws + OFF_IX);
  int bid = blockIdx.x, t = threadIdx.x;

  if (bid < 256) {  // p-writer: 64 batch rows per block, vectorized
    int b0 = bid * 64;
#pragma unroll
    for (int i = 0; i < 4; ++i) {
      int idx = t + i * 256, row = idx >> 4, c4 = idx & 15;
      float4 a4 = ((const float4*)att)[c4];
      float4 v = ((const float4*)(x + (size_t)(b0 + row) * 64))[c4];
      float* dst = &xa[row * XS + c4 * 4];
      dst[0] = v.x * a4.x; dst[1] = v.y * a4.y;
      dst[2] = v.z * a4.z; dst[3] = v.w * a4.w;
    }
    __syncthreads();
    int row2 = t >> 2, q = t & 3;
    const float* xr2 = &xa[row2 * XS];
    unsigned short* po = p_out + (size_t)(b0 + row2) * 256;
#pragma unroll
    for (int ks = 0; ks < 8; ++ks) {
      int fb = ks * 32 + q * 8;
      short8 vp;
      if (ks < 2) {                 // raw x_att
#pragma unroll
        for (int j = 0; j < 8; ++j) vp[j] = f2bf(xr2[fb + j]);
      } else if (ks < 4) {          // squares
#pragma unroll
        for (int j = 0; j < 8; ++j) { float u = xr2[fb - 64 + j]; vp[j] = f2bf(u * u); }
      } else {                      // interaction pairs
        const int2* pr = (const int2*)pairs + (fb - 128);
#pragma unroll
        for (int j = 0; j < 8; ++j) {
          int2 pq = pr[j];
          vp[j] = f2bf(xr2[pq.x] * xr2[pq.y]);
        }
      }
      *(short8*)(po + fb) = vp;
    }
  } else if (bid < 512) {  // cp cols 0..255 -> bf16 [1024][256]
    int e = (bid - 256) * 1024 + t * 4;
    int r = e >> 8, c = e & 255;
    const float* src = cp + (size_t)r * 257 + c;
#pragma unroll
    for (int q = 0; q < 4; ++q) cp_out[e + q] = f2bf(src[q]);
  } else if (bid < 516) {  // rule consts + bias
    int r = (bid - 512) * 256 + t;
    float p = pp[r];
    unsigned pk = 0;
#pragma unroll
    for (int l = 0; l < 4; ++l) {
      float m = mk[r * 4 + l], s = sg[r * 4 + l], tt = th[r * 4 + l];
      float A, C;
      if (m != 0.f) { A = -1.44269504f * p * s; C = 1.44269504f * p * s * tt; }
      else          { A = 0.f;                  C = -126.f; }  // exp2(-126) ~ 0 -> factor 1
      a2o[r * 4 + l] = A; c2o[r * 4 + l] = C;
      pk |= ((unsigned)fidx[r * 4 + l] & 0xFFu) << (8 * l);
    }
    ixo[r] = pk;
    cbo[r] = cp[(size_t)r * 257 + 256];  // ones-column coefficient
  } else {  // zero num/den (ws is re-poisoned 0xAA before every call)
    float* dst = (float*)(ws + (bid == 516 ? OFF_NUM : OFF_DEN));
#pragma unroll
    for (int q = 0; q < 64; ++q) dst[q * 256 + t] = 0.f;
  }
}

// ---- main: C[rule][batch] = cp . p^T (K=256) fused with firing.
// Hybrid operand plumbing (R4=41us LDS-both vs R6=63us stream-both):
//   B (p-tile, reused by all 4 waves)  -> LDS double-buffer, 1 barrier/step
//   A (cp, zero cross-wave reuse)      -> global stream, 2-deep reg pipeline
// grid (256 b x 8 r); block = 128 rules x 64 batches; LDS 24.8 KB.
__global__ __launch_bounds__(256, 4) void main_kernel(
    const unsigned char* __restrict__ ws,
    const float* __restrict__ x, const float* __restrict__ att,
    float* __restrict__ numg, float* __restrict__ deng)
{
  __shared__ float xa[64 * XS];     // 16640 B
  __shared__ short lP[2][64 * 32];  //  8192 B, 16B-block XOR swizzle

  const unsigned short* CP = (const unsigned short*)(ws + OFF_CP);
  const unsigned short* P  = (const unsigned short*)(ws + OFF_P);
  const float* CB = (const float*)(ws + OFF_CB);
  const float4* A2p = (const float4*)(ws + OFF_A2);
  const float4* C2p = (const float4*)(ws + OFF_C2);
  const unsigned* IX = (const unsigned*)(ws + OFF_IX);

  int t = threadIdx.x, l = t & 63, w = t >> 6;
  int g = l >> 4, lr = l & 15;
  int b0 = blockIdx.x * 64, r0 = blockIdx.y * 128;

  {  // stage x_att tile (64 rows x 64 f32) — feeds the firing epilogue
#pragma unroll
    for (int i = 0; i < 4; ++i) {
      int idx = t + i * 256, row = idx >> 4, c4 = idx & 15;
      float4 a4 = ((const float4*)att)[c4];
      float4 v = ((const float4*)(x + (size_t)(b0 + row) * 64))[c4];
      float* dst = &xa[row * XS + c4 * 4];
      dst[0] = v.x * a4.x; dst[1] = v.y * a4.y;
      dst[2] = v.z * a4.z; dst[3] = v.w * a4.w;
    }
  }

  // B staging ids: 64 rows x 4 chunks, one short8 per thread per step
  int srow = t >> 2, sq = t & 3;
  int sws = (srow ^ (srow >> 2)) & 3;
  const short8* pSrc = (const short8*)(P + (size_t)(b0 + srow) * 256) + sq;
  short* sDst0 = &lP[0][srow * 32 + ((sq ^ sws) * 8)];
  short* sDst1 = &lP[1][srow * 32 + ((sq ^ sws) * 8)];

  // A fragment bases (k-invariant per-lane addresses)
  const short8* aB0 = (const short8*)(CP + (size_t)(r0 + w * 32 + lr) * 256 + g * 8);
  const short8* aB1 = (const short8*)(CP + (size_t)(r0 + w * 32 + 16 + lr) * 256 + g * 8);

  auto rdB = [&](const short* buf, int ni) -> short8 {
    int row = ni * 16 + lr;
    int s = (row ^ (row >> 2)) & 3;
    return *(const short8*)&buf[row * 32 + ((g ^ s) * 8)];
  };

  // prologue: B ks0 -> lP[0]; bS <- ks1; A frags for ks0 & ks1 in regs
  short8 bS = pSrc[0];
  short8 a0_0 = aB0[0], a0_1 = aB1[0];   // even-step A pair
  short8 a1_0 = aB0[4], a1_1 = aB1[4];   // odd-step A pair
  *(short8*)sDst0 = bS;
  bS = pSrc[4];
  __syncthreads();  // xa + lP[0] ready

  f32x4 acc[2][4];
#pragma unroll
  for (int mi = 0; mi < 2; ++mi)
#pragma unroll
    for (int ni = 0; ni < 4; ++ni)
      acc[mi][ni] = (f32x4){0.f, 0.f, 0.f, 0.f};

  // STEP(KS): read lP[RBUF], 8 MFMA; write next tile to lP[WBUF]; refill
  // bS and the just-consumed A pair for KS+2. One barrier per step.
#define STEP(KS, RBUF, WBUF, AA0, AA1, LAST)                                   \
  {                                                                            \
    short8 bf0 = rdB(lP[RBUF], 0), bf1 = rdB(lP[RBUF], 1);                     \
    short8 bf2 = rdB(lP[RBUF], 2), bf3 = rdB(lP[RBUF], 3);                     \
    acc[0][0] = MF(AA0, bf0, acc[0][0]); acc[0][1] = MF(AA0, bf1, acc[0][1]);  \
    acc[0][2] = MF(AA0, bf2, acc[0][2]); acc[0][3] = MF(AA0, bf3, acc[0][3]);  \
    acc[1][0] = MF(AA1, bf0, acc[1][0]); acc[1][1] = MF(AA1, bf1, acc[1][1]);  \
    acc[1][2] = MF(AA1, bf2, acc[1][2]); acc[1][3] = MF(AA1, bf3, acc[1][3]);  \
    if (!(LAST)) {                                                             \
      *(short8*)sDst##WBUF = bS;                                               \
      if ((KS) + 2 < 8) {                                                      \
        bS = pSrc[((KS) + 2) * 4];                                             \
        AA0 = aB0[((KS) + 2) * 4]; AA1 = aB1[((KS) + 2) * 4];                  \
      }                                                                        \
      __syncthreads();                                                         \
    }                                                                          \
  }

  STEP(0, 0, 1, a0_0, a0_1, 0)
  STEP(1, 1, 0, a1_0, a1_1, 0)
  STEP(2, 0, 1, a0_0, a0_1, 0)
  STEP(3, 1, 0, a1_0, a1_1, 0)
  STEP(4, 0, 1, a0_0, a0_1, 0)
  STEP(5, 1, 0, a1_0, a1_1, 0)
  STEP(6, 0, 1, a0_0, a0_1, 0)
  STEP(7, 1, 0, a1_0, a1_1, 1)
#undef STEP

  // ---- fused firing epilogue. C layout: row = rule = w*32+mi*16+g*4+j
  // (g-uniform per 16 lanes), col = batch = ni*16+lr. Gather bank =
  // (16ni+lr+f)%32 on stride-65 xa: ~2-way (free).
  const float* xb0 = &xa[(0 * 16 + lr) * XS];
  const float* xb1 = &xa[(1 * 16 + lr) * XS];
  const float* xb2 = &xa[(2 * 16 + lr) * XS];
  const float* xb3 = &xa[(3 * 16 + lr) * XS];
  float num[4] = {0.f, 0.f, 0.f, 0.f}, den[4] = {0.f, 0.f, 0.f, 0.f};
#pragma unroll
  for (int mi = 0; mi < 2; ++mi) {
#pragma unroll
    for (int j = 0; j < 4; ++j) {
      int rule = r0 + w * 32 + mi * 16 + (g << 2) + j;
      float4 A2 = A2p[rule], C2 = C2p[rule];
      unsigned pk = IX[rule];
      float bias = CB[rule];
      int f0 = pk & 255, f1 = (pk >> 8) & 255, f2 = (pk >> 16) & 255, f3 = pk >> 24;
#pragma unroll
      for (int ni = 0; ni < 4; ++ni) {
        const float* xr = (ni == 0) ? xb0 : (ni == 1) ? xb1 : (ni == 2) ? xb2 : xb3;
        float e0 = __builtin_amdgcn_exp2f(fmaf(A2.x, xr[f0], C2.x));
        float e1 = __builtin_amdgcn_exp2f(fmaf(A2.y, xr[f1], C2.y));
        float e2 = __builtin_amdgcn_exp2f(fmaf(A2.z, xr[f2], C2.z));
        float e3 = __builtin_amdgcn_exp2f(fmaf(A2.w, xr[f3], C2.w));
        float D = 1.f;
        D = fmaf(D, e0, D); D = fmaf(D, e1, D);
        D = fmaf(D, e2, D); D = fmaf(D, e3, D);
        float fir = __builtin_amdgcn_rcpf(D);
        num[ni] = fmaf(fir, acc[mi][ni][j] + bias, num[ni]);
        den[ni] += fir;
      }
    }
  }

  // reduce over the 4 lane-groups (g) which hold different rules of same batch
#pragma unroll
  for (int ni = 0; ni < 4; ++ni) {
    float n = num[ni], d = den[ni];
    n += __shfl_xor(n, 16, 64); n += __shfl_xor(n, 32, 64);
    d += __shfl_xor(d, 16, 64); d += __shfl_xor(d, 32, 64);
    num[ni] = n; den[ni] = d;
  }
  float nv = 0.f, dv = 0.f;
#pragma unroll
  for (int ni = 0; ni < 4; ++ni)
    if (g == ni) { nv = num[ni]; dv = den[ni]; }
  atomicAdd(&numg[b0 + (g << 4) + lr], nv);
  atomicAdd(&deng[b0 + (g << 4) + lr], dv);
}

// ---------------- finalize ----------------
__global__ __launch_bounds__(256) void fin_kernel(
    const float* __restrict__ numg, const float* __restrict__ deng,
    float* __restrict__ y)
{
  int i = blockIdx.x * 256 + threadIdx.x;
  y[i] = numg[i] / (deng[i] + 1e-8f);
}

extern "C" void kernel_launch(void* const* d_in, const int* in_sizes, int n_in,
                              void* d_out, int out_size, void* d_ws, size_t ws_size,
                              hipStream_t stream) {
  (void)in_sizes; (void)n_in; (void)out_size; (void)ws_size;
  const float* x    = (const float*)d_in[0];
  const float* att  = (const float*)d_in[1];
  const float* pp   = (const float*)d_in[2];
  const float* th   = (const float*)d_in[3];
  const float* sg   = (const float*)d_in[4];
  const float* mk   = (const float*)d_in[5];
  const float* cp   = (const float*)d_in[6];
  const int* fidx   = (const int*)d_in[7];
  const int* pairs  = (const int*)d_in[8];
  unsigned char* ws = (unsigned char*)d_ws;
  float* numg = (float*)(ws + OFF_NUM);
  float* deng = (float*)(ws + OFF_DEN);

  prep_kernel<<<518, 256, 0, stream>>>(x, att, pp, th, sg, mk, cp, fidx, pairs, ws);
  main_kernel<<<dim3(256, 8), 256, 0, stream>>>(ws, x, att, numg, deng);
  fin_kernel<<<64, 256, 0, stream>>>(numg, deng, (float*)d_out);
}

// Round 8
// 106.874 us; speedup vs baseline: 1.2668x; 1.1056x over previous
//
#include <hip/hip_runtime.h>

typedef short short8 __attribute__((ext_vector_type(8)));
typedef float f32x4 __attribute__((ext_vector_type(4)));

// K = 256 (ones-column folded into per-rule bias); p materialized bf16.

// workspace layout (bytes)
#define OFF_CP   0ULL        // cp bf16 [1024][256]    524288
#define OFF_P    524288ULL   // p  bf16 [16384][256]  8388608
#define OFF_CB   8912896ULL  // bias f32 [1024]          4096
#define OFF_A2   8916992ULL  // a2 f32  [1024][4]       16384
#define OFF_C2   8933376ULL  // c2 f32  [1024][4]       16384
#define OFF_IX   8949760ULL  // packed fidx u32 [1024]   4096
#define OFF_NUM  8953856ULL  // num f32 [16384]         65536
#define OFF_DEN  9019392ULL  // den f32 [16384]         65536

#define XS 65  // xa LDS stride: gather bank = (row + f) % 32 -> ~2-way (free)

#define MF(a, b, c) __builtin_amdgcn_mfma_f32_16x16x32_bf16(a, b, c, 0, 0, 0)

__device__ __forceinline__ unsigned short f2bf(float f) {
  unsigned u = __float_as_uint(f);
  return (unsigned short)((u + 0x7FFFu + ((u >> 16) & 1u)) >> 16);
}

// ---- prep: p materialization, cp->bf16 + bias, rule consts, zero num/den ----
__global__ __launch_bounds__(256) void prep_kernel(
    const float* __restrict__ x, const float* __restrict__ att,
    const float* __restrict__ pp, const float* __restrict__ th,
    const float* __restrict__ sg, const float* __restrict__ mk,
    const float* __restrict__ cp, const int* __restrict__ fidx,
    const int* __restrict__ pairs, unsigned char* __restrict__ ws)
{
  __shared__ float xa[64 * XS];
  unsigned short* p_out  = (unsigned short*)(ws + OFF_P);
  unsigned short* cp_out = (unsigned short*)(ws + OFF_CP);
  float* cbo = (float*)(ws + OFF_CB);
  float* a2o = (float*)(ws + OFF_A2);
  float* c2o = (float*)(ws + OFF_C2);
  unsigned* ixo = (unsigned*)(ws + OFF_IX);
  int bid = blockIdx.x, t = threadIdx.x;

  if (bid < 256) {  // p-writer: 64 batch rows per block, vectorized
    int b0 = bid * 64;
#pragma unroll
    for (int i = 0; i < 4; ++i) {
      int idx = t + i * 256, row = idx >> 4, c4 = idx & 15;
      float4 a4 = ((const float4*)att)[c4];
      float4 v = ((const float4*)(x + (size_t)(b0 + row) * 64))[c4];
      float* dst = &xa[row * XS + c4 * 4];
      dst[0] = v.x * a4.x; dst[1] = v.y * a4.y;
      dst[2] = v.z * a4.z; dst[3] = v.w * a4.w;
    }
    __syncthreads();
    int row2 = t >> 2, q = t & 3;
    const float* xr2 = &xa[row2 * XS];
    unsigned short* po = p_out + (size_t)(b0 + row2) * 256;
#pragma unroll
    for (int ks = 0; ks < 8; ++ks) {
      int fb = ks * 32 + q * 8;
      short8 vp;
      if (ks < 2) {                 // raw x_att
#pragma unroll
        for (int j = 0; j < 8; ++j) vp[j] = f2bf(xr2[fb + j]);
      } else if (ks < 4) {          // squares
#pragma unroll
        for (int j = 0; j < 8; ++j) { float u = xr2[fb - 64 + j]; vp[j] = f2bf(u * u); }
      } else {                      // interaction pairs
        const int2* pr = (const int2*)pairs + (fb - 128);
#pragma unroll
        for (int j = 0; j < 8; ++j) {
          int2 pq = pr[j];
          vp[j] = f2bf(xr2[pq.x] * xr2[pq.y]);
        }
      }
      *(short8*)(po + fb) = vp;
    }
  } else if (bid < 512) {  // cp cols 0..255 -> bf16 [1024][256]
    int e = (bid - 256) * 1024 + t * 4;
    int r = e >> 8, c = e & 255;
    const float* src = cp + (size_t)r * 257 + c;
#pragma unroll
    for (int q = 0; q < 4; ++q) cp_out[e + q] = f2bf(src[q]);
  } else if (bid < 516) {  // rule consts + bias
    int r = (bid - 512) * 256 + t;
    float p = pp[r];
    unsigned pk = 0;
#pragma unroll
    for (int l = 0; l < 4; ++l) {
      float m = mk[r * 4 + l], s = sg[r * 4 + l], tt = th[r * 4 + l];
      float A, C;
      if (m != 0.f) { A = -1.44269504f * p * s; C = 1.44269504f * p * s * tt; }
      else          { A = 0.f;                  C = -126.f; }  // exp2(-126) ~ 0 -> factor 1
      a2o[r * 4 + l] = A; c2o[r * 4 + l] = C;
      pk |= ((unsigned)fidx[r * 4 + l] & 0xFFu) << (8 * l);
    }
    ixo[r] = pk;
    cbo[r] = cp[(size_t)r * 257 + 256];  // ones-column coefficient
  } else {  // zero num/den (ws is re-poisoned 0xAA before every call)
    float* dst = (float*)(ws + (bid == 516 ? OFF_NUM : OFF_DEN));
#pragma unroll
    for (int q = 0; q < 64; ++q) dst[q * 256 + t] = 0.f;
  }
}

// ---- main: C[rule][batch] = cp . p^T (K=256) fused with firing.
// Hybrid operand plumbing (R4=41us LDS-both vs R6=63us stream-both):
//   B (p-tile, reused by all 4 waves)  -> LDS double-buffer, 1 barrier/step
//   A (cp, zero cross-wave reuse)      -> global stream, 2-deep reg pipeline
// launch_bounds (256,3): 170-reg unified cap. R7's (256,4)=128 cap spilled
// 57 MB (WRITE_SIZE); this structure needs ~150 regs. 3 blocks/CU over a
// 2048-block grid -> rounds 3/3/2 (small tail).
__global__ __launch_bounds__(256, 3) void main_kernel(
    const unsigned char* __restrict__ ws,
    const float* __restrict__ x, const float* __restrict__ att,
    float* __restrict__ numg, float* __restrict__ deng)
{
  __shared__ float xa[64 * XS];     // 16640 B
  __shared__ short lP[2][64 * 32];  //  8192 B, 16B-block XOR swizzle

  const unsigned short* CP = (const unsigned short*)(ws + OFF_CP);
  const unsigned short* P  = (const unsigned short*)(ws + OFF_P);
  const float* CB = (const float*)(ws + OFF_CB);
  const float4* A2p = (const float4*)(ws + OFF_A2);
  const float4* C2p = (const float4*)(ws + OFF_C2);
  const unsigned* IX = (const unsigned*)(ws + OFF_IX);

  int t = threadIdx.x, l = t & 63, w = t >> 6;
  int g = l >> 4, lr = l & 15;
  int b0 = blockIdx.x * 64, r0 = blockIdx.y * 128;

  {  // stage x_att tile (64 rows x 64 f32) — feeds the firing epilogue
#pragma unroll
    for (int i = 0; i < 4; ++i) {
      int idx = t + i * 256, row = idx >> 4, c4 = idx & 15;
      float4 a4 = ((const float4*)att)[c4];
      float4 v = ((const float4*)(x + (size_t)(b0 + row) * 64))[c4];
      float* dst = &xa[row * XS + c4 * 4];
      dst[0] = v.x * a4.x; dst[1] = v.y * a4.y;
      dst[2] = v.z * a4.z; dst[3] = v.w * a4.w;
    }
  }

  // B staging ids: 64 rows x 4 chunks, one short8 per thread per step
  int srow = t >> 2, sq = t & 3;
  int sws = (srow ^ (srow >> 2)) & 3;
  const short8* pSrc = (const short8*)(P + (size_t)(b0 + srow) * 256) + sq;
  short* sDst0 = &lP[0][srow * 32 + ((sq ^ sws) * 8)];
  short* sDst1 = &lP[1][srow * 32 + ((sq ^ sws) * 8)];

  // A fragment bases (k-invariant per-lane addresses)
  const short8* aB0 = (const short8*)(CP + (size_t)(r0 + w * 32 + lr) * 256 + g * 8);
  const short8* aB1 = (const short8*)(CP + (size_t)(r0 + w * 32 + 16 + lr) * 256 + g * 8);

  auto rdB = [&](const short* buf, int ni) -> short8 {
    int row = ni * 16 + lr;
    int s = (row ^ (row >> 2)) & 3;
    return *(const short8*)&buf[row * 32 + ((g ^ s) * 8)];
  };

  // prologue: B ks0 -> lP[0]; bS <- ks1; A frags for ks0 & ks1 in regs
  short8 bS = pSrc[0];
  short8 a0_0 = aB0[0], a0_1 = aB1[0];   // even-step A pair
  short8 a1_0 = aB0[4], a1_1 = aB1[4];   // odd-step A pair
  *(short8*)sDst0 = bS;
  bS = pSrc[4];
  __syncthreads();  // xa + lP[0] ready

  f32x4 acc[2][4];
#pragma unroll
  for (int mi = 0; mi < 2; ++mi)
#pragma unroll
    for (int ni = 0; ni < 4; ++ni)
      acc[mi][ni] = (f32x4){0.f, 0.f, 0.f, 0.f};

  // STEP(KS): read lP[RBUF], 8 MFMA; write next tile to lP[WBUF]; refill
  // bS and the just-consumed A pair for KS+2. One barrier per step.
#define STEP(KS, RBUF, WBUF, AA0, AA1, LAST)                                   \
  {                                                                            \
    short8 bf0 = rdB(lP[RBUF], 0), bf1 = rdB(lP[RBUF], 1);                     \
    short8 bf2 = rdB(lP[RBUF], 2), bf3 = rdB(lP[RBUF], 3);                     \
    acc[0][0] = MF(AA0, bf0, acc[0][0]); acc[0][1] = MF(AA0, bf1, acc[0][1]);  \
    acc[0][2] = MF(AA0, bf2, acc[0][2]); acc[0][3] = MF(AA0, bf3, acc[0][3]);  \
    acc[1][0] = MF(AA1, bf0, acc[1][0]); acc[1][1] = MF(AA1, bf1, acc[1][1]);  \
    acc[1][2] = MF(AA1, bf2, acc[1][2]); acc[1][3] = MF(AA1, bf3, acc[1][3]);  \
    if (!(LAST)) {                                                             \
      *(short8*)sDst##WBUF = bS;                                               \
      if ((KS) + 2 < 8) {                                                      \
        bS = pSrc[((KS) + 2) * 4];                                             \
        AA0 = aB0[((KS) + 2) * 4]; AA1 = aB1[((KS) + 2) * 4];                  \
      }                                                                        \
      __syncthreads();                                                         \
    }                                                                          \
  }

  STEP(0, 0, 1, a0_0, a0_1, 0)
  STEP(1, 1, 0, a1_0, a1_1, 0)
  STEP(2, 0, 1, a0_0, a0_1, 0)
  STEP(3, 1, 0, a1_0, a1_1, 0)
  STEP(4, 0, 1, a0_0, a0_1, 0)
  STEP(5, 1, 0, a1_0, a1_1, 0)
  STEP(6, 0, 1, a0_0, a0_1, 0)
  STEP(7, 1, 0, a1_0, a1_1, 1)
#undef STEP

  // ---- fused firing epilogue. C layout: row = rule = w*32+mi*16+g*4+j
  // (g-uniform per 16 lanes), col = batch = ni*16+lr. Gather bank =
  // (16ni+lr+f)%32 on stride-65 xa: ~2-way (free).
  const float* xb0 = &xa[(0 * 16 + lr) * XS];
  const float* xb1 = &xa[(1 * 16 + lr) * XS];
  const float* xb2 = &xa[(2 * 16 + lr) * XS];
  const float* xb3 = &xa[(3 * 16 + lr) * XS];
  float num[4] = {0.f, 0.f, 0.f, 0.f}, den[4] = {0.f, 0.f, 0.f, 0.f};
#pragma unroll
  for (int mi = 0; mi < 2; ++mi) {
#pragma unroll
    for (int j = 0; j < 4; ++j) {
      int rule = r0 + w * 32 + mi * 16 + (g << 2) + j;
      float4 A2 = A2p[rule], C2 = C2p[rule];
      unsigned pk = IX[rule];
      float bias = CB[rule];
      int f0 = pk & 255, f1 = (pk >> 8) & 255, f2 = (pk >> 16) & 255, f3 = pk >> 24;
#pragma unroll
      for (int ni = 0; ni < 4; ++ni) {
        const float* xr = (ni == 0) ? xb0 : (ni == 1) ? xb1 : (ni == 2) ? xb2 : xb3;
        float e0 = __builtin_amdgcn_exp2f(fmaf(A2.x, xr[f0], C2.x));
        float e1 = __builtin_amdgcn_exp2f(fmaf(A2.y, xr[f1], C2.y));
        float e2 = __builtin_amdgcn_exp2f(fmaf(A2.z, xr[f2], C2.z));
        float e3 = __builtin_amdgcn_exp2f(fmaf(A2.w, xr[f3], C2.w));
        float D = 1.f;
        D = fmaf(D, e0, D); D = fmaf(D, e1, D);
        D = fmaf(D, e2, D); D = fmaf(D, e3, D);
        float fir = __builtin_amdgcn_rcpf(D);
        num[ni] = fmaf(fir, acc[mi][ni][j] + bias, num[ni]);
        den[ni] += fir;
      }
    }
  }

  // reduce over the 4 lane-groups (g) which hold different rules of same batch
#pragma unroll
  for (int ni = 0; ni < 4; ++ni) {
    float n = num[ni], d = den[ni];
    n += __shfl_xor(n, 16, 64); n += __shfl_xor(n, 32, 64);
    d += __shfl_xor(d, 16, 64); d += __shfl_xor(d, 32, 64);
    num[ni] = n; den[ni] = d;
  }
  float nv = 0.f, dv = 0.f;
#pragma unroll
  for (int ni = 0; ni < 4; ++ni)
    if (g == ni) { nv = num[ni]; dv = den[ni]; }
  atomicAdd(&numg[b0 + (g << 4) + lr], nv);
  atomicAdd(&deng[b0 + (g << 4) + lr], dv);
}

// ---------------- finalize ----------------
__global__ __launch_bounds__(256) void fin_kernel(
    const float* __restrict__ numg, const float* __restrict__ deng,
    float* __restrict__ y)
{
  int i = blockIdx.x * 256 + threadIdx.x;
  y[i] = numg[i] / (deng[i] + 1e-8f);
}

extern "C" void kernel_launch(void* const* d_in, const int* in_sizes, int n_in,
                              void* d_out, int out_size, void* d_ws, size_t ws_size,
                              hipStream_t stream) {
  (void)in_sizes; (void)n_in; (void)out_size; (void)ws_size;
  const float* x    = (const float*)d_in[0];
  const float* att  = (const float*)d_in[1];
  const float* pp   = (const float*)d_in[2];
  const float* th   = (const float*)d_in[3];
  const float* sg   = (const float*)d_in[4];
  const float* mk   = (const float*)d_in[5];
  const float* cp   = (const float*)d_in[6];
  const int* fidx   = (const int*)d_in[7];
  const int* pairs  = (const int*)d_in[8];
  unsigned char* ws = (unsigned char*)d_ws;
  float* numg = (float*)(ws + OFF_NUM);
  float* deng = (float*)(ws + OFF_DEN);

  prep_kernel<<<518, 256, 0, stream>>>(x, att, pp, th, sg, mk, cp, fidx, pairs, ws);
  main_kernel<<<dim3(256, 8), 256, 0, stream>>>(ws, x, att, numg, deng);
  fin_kernel<<<64, 256, 0, stream>>>(numg, deng, (float*)d_out);
}